// Round 6
// baseline (126.054 us; speedup 1.0000x reference)
//
#include <hip/hip_runtime.h>

#define BATCH   8192
#define SDIM    64
#define HDIM    128
#define NB      8      // batch rows per block (4 per thread, 2 row-groups)
#define PAD     12     // LDS row stride in floats (8 data + 4 pad, 16B-aligned)
#define UNFOLDS 4

typedef float f32x2 __attribute__((ext_vector_type(2)));
typedef float f32x4 __attribute__((ext_vector_type(4)));

__device__ __forceinline__ f32x2 sigmoid2(f32x2 z) {
    f32x2 e;
    e.x = __builtin_amdgcn_exp2f(z.x);
    e.y = __builtin_amdgcn_exp2f(z.y);
    f32x2 d = e + (f32x2){1.0f, 1.0f};
    f32x2 r;
    r.x = __builtin_amdgcn_rcpf(d.x);
    r.y = __builtin_amdgcn_rcpf(d.y);
    return r;
}

// acc over 4 rows packed in xv (f32x4), params P = {a, c, w, 0}
__device__ __forceinline__ void sig_acc(f32x4 P, f32x4 xv,
                                        f32x2& acc0, f32x2& acc1) {
    f32x2 av = {P.x, P.x}, cv = {P.y, P.y}, wv = {P.z, P.z};
    f32x2 r0 = sigmoid2(__builtin_elementwise_fma(xv.xy, av, cv));
    f32x2 r1 = sigmoid2(__builtin_elementwise_fma(xv.zw, av, cv));
    acc0 = __builtin_elementwise_fma(wv, r0, acc0);
    acc1 = __builtin_elementwise_fma(wv, r1, acc1);
}

// Pack {a, c, w, 0} per synapse: a = -log2e*sigma, c = -a*mu.
__global__ __launch_bounds__(256) void prep_kernel(
    const float* __restrict__ s_mu, const float* __restrict__ s_sig,
    const float* __restrict__ s_W,
    const float* __restrict__ h_mu, const float* __restrict__ h_sig,
    const float* __restrict__ h_W,
    f32x4* __restrict__ hpk, f32x4* __restrict__ spk)
{
    const float LOG2E = 1.4426950408889634f;
    int i = blockIdx.x * 256 + threadIdx.x;
    if (i < HDIM * HDIM) {
        float a = -LOG2E * h_sig[i];
        hpk[i] = (f32x4){a, -a * h_mu[i], h_W[i], 0.0f};
    }
    if (i < SDIM * HDIM) {
        float a = -LOG2E * s_sig[i];
        spk[i] = (f32x4){a, -a * s_mu[i], s_W[i], 0.0f};
    }
}

__global__ __launch_bounds__(256) void ltc_main(
    const float* __restrict__ input,    // [B,S]
    const float* __restrict__ hidden,   // [B,H]
    const f32x4* __restrict__ spk,      // [S,H] packed {a,c,w,0}
    const f32x4* __restrict__ hpk,      // [H,H] packed {a,c,w,0}
    const float* __restrict__ w_tau,    // [H]
    const float* __restrict__ w_A,      // [H]
    const float* __restrict__ elapsed,  // [1]
    float* __restrict__ out)            // [B,H]
{
    const int tid = threadIdx.x;
    const int h   = tid & (HDIM - 1);    // output feature
    const int g   = tid >> 7;            // row-group 0/1 -> rows 4g..4g+3
    const int b0  = blockIdx.x * NB;

    // Transposed, padded tiles: [pos][row-slot]; one ds_read_b128 = 4 rows.
    __shared__ float st [HDIM][PAD];     // 6 KB
    __shared__ float xin[SDIM][PAD];     // 3 KB

    for (int i = tid; i < NB * SDIM; i += 256) {
        int r = i >> 6, s = i & (SDIM - 1);
        xin[s][r] = input[(b0 + r) * SDIM + s];
    }
    for (int i = tid; i < NB * HDIM; i += 256) {
        int r = i >> 7, p = i & (HDIM - 1);
        st[p][r] = hidden[(b0 + r) * HDIM + p];
    }
    __syncthreads();

    const float dt = elapsed[0] * (1.0f / UNFOLDS);

#define LD4(arr, idx) (*(const f32x4*)&(arr)[idx][g * 4])

    // ---- sensory activation, 4-deep software pipeline ----
    f32x2 sens0 = {0.0f, 0.0f}, sens1 = {0.0f, 0.0f};
    {
        f32x4 Pa = spk[0 * HDIM + h], Pb = spk[1 * HDIM + h];
        f32x4 Pc = spk[2 * HDIM + h], Pd = spk[3 * HDIM + h];
        f32x4 xa = LD4(xin, 0), xb = LD4(xin, 1);
        f32x4 xc = LD4(xin, 2), xd = LD4(xin, 3);
        for (int s = 0; s < SDIM; s += 4) {
            int q = (s + 4 < SDIM) ? s + 4 : s;    // clamped prefetch base
            f32x4 Pe = spk[(q + 0) * HDIM + h], Pf = spk[(q + 1) * HDIM + h];
            f32x4 Pg = spk[(q + 2) * HDIM + h], Ph = spk[(q + 3) * HDIM + h];
            f32x4 xe = LD4(xin, q + 0), xf = LD4(xin, q + 1);
            f32x4 xg = LD4(xin, q + 2), xh = LD4(xin, q + 3);
            sig_acc(Pa, xa, sens0, sens1);
            sig_acc(Pb, xb, sens0, sens1);
            sig_acc(Pc, xc, sens0, sens1);
            sig_acc(Pd, xd, sens0, sens1);
            Pa = Pe; Pb = Pf; Pc = Pg; Pd = Ph;
            xa = xe; xb = xf; xc = xg; xd = xh;
        }
    }

    const float wT  = w_tau[h];
    const float wA  = w_A[h];
    const float dA  = dt * wA;
    const float dT1 = fmaf(dt, wT, 1.0f) + 1e-8f;   // 1 + dt*w_tau + EPS
    const f32x2 dAv  = {dA, dA};
    const f32x2 dtv  = {dt, dt};
    const f32x2 dT1v = {dT1, dT1};

    f32x4 ns;

    // ---- ODE unfolds ----
    for (int it = 0; it < UNFOLDS; ++it) {
        f32x2 acc0 = sens0, acc1 = sens1;

        {
            f32x4 Pa = hpk[0 * HDIM + h], Pb = hpk[1 * HDIM + h];
            f32x4 Pc = hpk[2 * HDIM + h], Pd = hpk[3 * HDIM + h];
            f32x4 xa = LD4(st, 0), xb = LD4(st, 1);
            f32x4 xc = LD4(st, 2), xd = LD4(st, 3);
            for (int p = 0; p < HDIM; p += 4) {
                int q = (p + 4 < HDIM) ? p + 4 : p;   // clamped prefetch base
                f32x4 Pe = hpk[(q + 0) * HDIM + h], Pf = hpk[(q + 1) * HDIM + h];
                f32x4 Pg = hpk[(q + 2) * HDIM + h], Ph = hpk[(q + 3) * HDIM + h];
                f32x4 xe = LD4(st, q + 0), xf = LD4(st, q + 1);
                f32x4 xg = LD4(st, q + 2), xh = LD4(st, q + 3);
                sig_acc(Pa, xa, acc0, acc1);
                sig_acc(Pb, xb, acc0, acc1);
                sig_acc(Pc, xc, acc0, acc1);
                sig_acc(Pd, xd, acc0, acc1);
                Pa = Pe; Pb = Pf; Pc = Pg; Pd = Ph;
                xa = xe; xb = xf; xc = xg; xd = xh;
            }
        }

        // new state = (st + dA*resp) / (1 + dt*w_tau + dt*resp + eps)
        f32x4 old = LD4(st, h);
        f32x2 n0 = __builtin_elementwise_fma(dAv, acc0, old.xy);
        f32x2 n1 = __builtin_elementwise_fma(dAv, acc1, old.zw);
        f32x2 d0 = __builtin_elementwise_fma(dtv, acc0, dT1v);
        f32x2 d1 = __builtin_elementwise_fma(dtv, acc1, dT1v);
        ns.x = n0.x * __builtin_amdgcn_rcpf(d0.x);
        ns.y = n0.y * __builtin_amdgcn_rcpf(d0.y);
        ns.z = n1.x * __builtin_amdgcn_rcpf(d1.x);
        ns.w = n1.y * __builtin_amdgcn_rcpf(d1.y);

        __syncthreads();                 // all reads of st done before overwrite
        *(f32x4*)&st[h][g * 4] = ns;
        __syncthreads();                 // writes visible before next unfold
    }

    // ---- output: this thread owns rows 4g..4g+3 at feature h ----
    out[(b0 + g * 4 + 0) * HDIM + h] = ns.x;
    out[(b0 + g * 4 + 1) * HDIM + h] = ns.y;
    out[(b0 + g * 4 + 2) * HDIM + h] = ns.z;
    out[(b0 + g * 4 + 3) * HDIM + h] = ns.w;
}

extern "C" void kernel_launch(void* const* d_in, const int* in_sizes, int n_in,
                              void* d_out, int out_size, void* d_ws, size_t ws_size,
                              hipStream_t stream) {
    const float* input   = (const float*)d_in[0];
    const float* hidden  = (const float*)d_in[1];
    const float* s_mu    = (const float*)d_in[2];
    const float* s_sig   = (const float*)d_in[3];
    const float* s_W     = (const float*)d_in[4];
    const float* h_mu    = (const float*)d_in[5];
    const float* h_sig   = (const float*)d_in[6];
    const float* h_W     = (const float*)d_in[7];
    const float* w_tau   = (const float*)d_in[8];
    const float* w_A     = (const float*)d_in[9];
    const float* elapsed = (const float*)d_in[10];
    float* out = (float*)d_out;

    // workspace: hpk [H*H] float4 (256 KB) then spk [S*H] float4 (128 KB)
    f32x4* hpk = (f32x4*)d_ws;
    f32x4* spk = hpk + HDIM * HDIM;

    prep_kernel<<<dim3((HDIM * HDIM + 255) / 256), dim3(256), 0, stream>>>(
        s_mu, s_sig, s_W, h_mu, h_sig, h_W, hpk, spk);

    ltc_main<<<dim3(BATCH / NB), dim3(256), 0, stream>>>(
        input, hidden, spk, hpk, w_tau, w_A, elapsed, out);
}